// Round 1
// baseline (363.735 us; speedup 1.0000x reference)
//
#include <hip/hip_runtime.h>
#include <hip/hip_bf16.h>
#include <stdint.h>

#define T_TOK 2048
#define H_DIM 2048
#define I_DIM 1408
#define NEXP  8
#define NPOS  4096   // T_TOK * top_k
#define NPAD  4224   // NPOS + 128 pad rows (tile overrun safety)

typedef short short8 __attribute__((ext_vector_type(8)));
typedef float f32x4  __attribute__((ext_vector_type(4)));

// f32 -> bf16 RNE (finite inputs only)
__device__ __forceinline__ short f2bf(float f) {
  union { float f; uint32_t u; } v; v.f = f;
  uint32_t r = (v.u + 0x7FFFu + ((v.u >> 16) & 1u)) >> 16;
  return (short)r;
}

// async global->LDS, 16B per lane. LDS dest = wave-uniform base + lane*16.
__device__ __forceinline__ void load_lds16(const void* g, void* l) {
  __builtin_amdgcn_global_load_lds((const __attribute__((address_space(1))) uint32_t*)g,
                                   (__attribute__((address_space(3))) uint32_t*)l,
                                   16, 0, 0);
}

// ---------------------------------------------------------------------------
// Kernel 1: routing. Single block. top-2 of 8 logits per token, normalized
// weights, per-expert grouping (pos -> token, weight), expert offsets.
// ---------------------------------------------------------------------------
__global__ void k_routing(const float* __restrict__ logits,
                          int* __restrict__ pos_token,
                          float* __restrict__ pos_w,
                          int* __restrict__ eoff) {
  __shared__ int   s_ids[T_TOK];
  __shared__ float s_w0[T_TOK];
  __shared__ float s_w1[T_TOK];
  __shared__ int s_cnt[NEXP], s_cur[NEXP], s_off[NEXP + 1];
  const int tid = threadIdx.x;
  if (tid < NEXP) { s_cnt[tid] = 0; s_cur[tid] = 0; }
  __syncthreads();

  for (int t = tid; t < T_TOK; t += blockDim.x) {
    float l[NEXP];
#pragma unroll
    for (int e = 0; e < NEXP; ++e) l[e] = logits[t * NEXP + e];
    int b0 = 0; float v0 = l[0];
#pragma unroll
    for (int e = 1; e < NEXP; ++e) if (l[e] > v0) { v0 = l[e]; b0 = e; }
    int b1 = -1; float v1 = -1e30f;
#pragma unroll
    for (int e = 0; e < NEXP; ++e) if (e != b0 && l[e] > v1) { v1 = l[e]; b1 = e; }
    // softmax + top2 renorm collapses to a 2-way softmax over (v0, v1)
    float t1 = __expf(v1 - v0);
    float w0 = 1.f / (1.f + t1);
    float w1 = 1.f - w0;
    s_ids[t] = b0 | (b1 << 8);
    s_w0[t] = w0; s_w1[t] = w1;
    atomicAdd(&s_cnt[b0], 1);
    atomicAdd(&s_cnt[b1], 1);
  }
  __syncthreads();
  if (tid == 0) {
    int acc = 0;
    for (int e = 0; e < NEXP; ++e) { s_off[e] = acc; acc += s_cnt[e]; }
    s_off[NEXP] = acc;
    for (int e = 0; e <= NEXP; ++e) eoff[e] = s_off[e];
  }
  __syncthreads();
  for (int t = tid; t < T_TOK; t += blockDim.x) {
    int ids = s_ids[t];
    int e0 = ids & 255, e1 = ids >> 8;
    int p0 = s_off[e0] + atomicAdd(&s_cur[e0], 1);
    pos_token[p0] = t; pos_w[p0] = s_w0[t];
    int p1 = s_off[e1] + atomicAdd(&s_cur[e1], 1);
    pos_token[p1] = t; pos_w[p1] = s_w1[t];
  }
}

// ---------------------------------------------------------------------------
// Kernel 2: gather+cast x rows into grouped order, bf16.
// One block per pos row; 256 threads x 8 elems.
// ---------------------------------------------------------------------------
__global__ void k_gather(const float* __restrict__ x,
                         const int* __restrict__ pos_token,
                         short* __restrict__ xg) {
  const int p = blockIdx.x;
  const int tid = threadIdx.x;
  const int tok = pos_token[p];
  const float4* src = (const float4*)(x + (size_t)tok * H_DIM);
  float4 a = src[tid * 2];
  float4 b = src[tid * 2 + 1];
  short8 s;
  s[0] = f2bf(a.x); s[1] = f2bf(a.y); s[2] = f2bf(a.z); s[3] = f2bf(a.w);
  s[4] = f2bf(b.x); s[5] = f2bf(b.y); s[6] = f2bf(b.z); s[7] = f2bf(b.w);
  ((short8*)(xg + (size_t)p * H_DIM))[tid] = s;
}

// ---------------------------------------------------------------------------
// Kernel 3: grouped GEMM1: act = silu(xg @ w13_gate^T) * (xg @ w13_up^T)
// A: [128m x 32k] bf16 LDS (XOR-swizzled, 4 slots of 16B per 64B row)
// B: [128n x 32k] f32 LDS (XOR-swizzled, 8 slots of 16B per 128B row),
//    converted to bf16 in-register per fragment.
// 4 waves as 2x2, each wave 64x64 per half (gate + up accumulators).
// ---------------------------------------------------------------------------
__global__ __launch_bounds__(256, 1) void k_gateup(
    const short* __restrict__ xg, const float* __restrict__ w13,
    const int* __restrict__ eoff, short* __restrict__ act) {
  __shared__ short a_s[128 * 32];   // 8 KB
  __shared__ float bg_s[128 * 32];  // 16 KB
  __shared__ float bu_s[128 * 32];  // 16 KB

  const int e = blockIdx.z;
  const int off = eoff[e];
  const int cnt = eoff[e + 1] - off;
  const int mt = blockIdx.y;
  if (mt * 128 >= cnt) return;
  const int nt = blockIdx.x;
  const int tid = threadIdx.x;
  const int wid = tid >> 6;
  const int lane = tid & 63;
  const int wm = wid >> 1, wn = wid & 1;

  f32x4 accg[4][4] = {};
  f32x4 accu[4][4] = {};

  const short* aG  = xg + (size_t)(off + mt * 128) * H_DIM;
  const float* bgG = w13 + (size_t)e * (2 * I_DIM) * H_DIM + (size_t)(nt * 128) * H_DIM;
  const float* buG = bgG + (size_t)I_DIM * H_DIM;

  // staging source coords (inverse-swizzled so LDS slot s holds logical P(s))
  const int arow = tid >> 2;
  const int acol = ((tid & 3) ^ ((tid >> 3) & 3)) * 8;  // elems
  const int brow = tid >> 3;
  const int bcol = ((tid & 7) ^ ((tid >> 3) & 7)) * 4;  // f32 elems

  char* aDst  = (char*)a_s  + (size_t)wid * 1024;
  char* bgDst = (char*)bg_s + (size_t)wid * 1024;
  char* buDst = (char*)bu_s + (size_t)wid * 1024;

  for (int ks = 0; ks < H_DIM; ks += 32) {
#pragma unroll
    for (int i = 0; i < 2; ++i)
      load_lds16(aG + (size_t)(i * 64 + arow) * H_DIM + ks + acol, aDst + i * 4096);
#pragma unroll
    for (int i = 0; i < 4; ++i) {
      load_lds16(bgG + (size_t)(i * 32 + brow) * H_DIM + ks + bcol, bgDst + i * 4096);
      load_lds16(buG + (size_t)(i * 32 + brow) * H_DIM + ks + bcol, buDst + i * 4096);
    }
    __syncthreads();

    short8 af[4];
    const int asl = (lane >> 4) ^ ((lane >> 1) & 3);
#pragma unroll
    for (int fm = 0; fm < 4; ++fm) {
      int m = wm * 64 + fm * 16 + (lane & 15);
      af[fm] = *(const short8*)((const char*)a_s + m * 64 + asl * 16);
    }
    const int k8 = (lane >> 4) * 8;
#pragma unroll
    for (int fn = 0; fn < 4; ++fn) {
      int n = wn * 64 + fn * 16 + (lane & 15);
      int s0 = (k8 >> 2) ^ (n & 7);
      int s1 = ((k8 >> 2) + 1) ^ (n & 7);
      f32x4 g0 = *(const f32x4*)(bg_s + n * 32 + s0 * 4);
      f32x4 g1 = *(const f32x4*)(bg_s + n * 32 + s1 * 4);
      short8 bg;
#pragma unroll
      for (int j = 0; j < 4; ++j) { bg[j] = f2bf(g0[j]); bg[j + 4] = f2bf(g1[j]); }
#pragma unroll
      for (int fm = 0; fm < 4; ++fm)
        accg[fm][fn] = __builtin_amdgcn_mfma_f32_16x16x32_bf16(af[fm], bg, accg[fm][fn], 0, 0, 0);
      f32x4 u0 = *(const f32x4*)(bu_s + n * 32 + s0 * 4);
      f32x4 u1 = *(const f32x4*)(bu_s + n * 32 + s1 * 4);
      short8 bu;
#pragma unroll
      for (int j = 0; j < 4; ++j) { bu[j] = f2bf(u0[j]); bu[j + 4] = f2bf(u1[j]); }
#pragma unroll
      for (int fm = 0; fm < 4; ++fm)
        accu[fm][fn] = __builtin_amdgcn_mfma_f32_16x16x32_bf16(af[fm], bu, accu[fm][fn], 0, 0, 0);
    }
    __syncthreads();
  }

  // epilogue: silu(g)*u -> bf16 act
#pragma unroll
  for (int fm = 0; fm < 4; ++fm) {
#pragma unroll
    for (int r = 0; r < 4; ++r) {
      int m = wm * 64 + fm * 16 + (lane >> 4) * 4 + r;
      if (mt * 128 + m < cnt) {
        size_t grow = (size_t)(off + mt * 128 + m);
#pragma unroll
        for (int fn = 0; fn < 4; ++fn) {
          int col = nt * 128 + wn * 64 + fn * 16 + (lane & 15);
          float g = accg[fm][fn][r];
          float u = accu[fm][fn][r];
          float a = g / (1.f + __expf(-g)) * u;
          act[grow * I_DIM + col] = f2bf(a);
        }
      }
    }
  }
}

// ---------------------------------------------------------------------------
// Kernel 4: grouped GEMM2: out[tok] += w * (act @ w2[e]^T). Same structure.
// ---------------------------------------------------------------------------
__global__ __launch_bounds__(256, 1) void k_down(
    const short* __restrict__ act, const float* __restrict__ w2,
    const int* __restrict__ eoff, const int* __restrict__ pos_token,
    const float* __restrict__ pos_w, float* __restrict__ out) {
  __shared__ short a_s[128 * 32];  // 8 KB
  __shared__ float b_s[128 * 32];  // 16 KB

  const int e = blockIdx.z;
  const int off = eoff[e];
  const int cnt = eoff[e + 1] - off;
  const int mt = blockIdx.y;
  if (mt * 128 >= cnt) return;
  const int nt = blockIdx.x;
  const int tid = threadIdx.x;
  const int wid = tid >> 6;
  const int lane = tid & 63;
  const int wm = wid >> 1, wn = wid & 1;

  f32x4 acc[4][4] = {};

  const short* aG = act + (size_t)(off + mt * 128) * I_DIM;
  const float* bG = w2 + (size_t)e * H_DIM * I_DIM + (size_t)(nt * 128) * I_DIM;

  const int arow = tid >> 2;
  const int acol = ((tid & 3) ^ ((tid >> 3) & 3)) * 8;
  const int brow = tid >> 3;
  const int bcol = ((tid & 7) ^ ((tid >> 3) & 7)) * 4;

  char* aDst = (char*)a_s + (size_t)wid * 1024;
  char* bDst = (char*)b_s + (size_t)wid * 1024;

  for (int ks = 0; ks < I_DIM; ks += 32) {
#pragma unroll
    for (int i = 0; i < 2; ++i)
      load_lds16(aG + (size_t)(i * 64 + arow) * I_DIM + ks + acol, aDst + i * 4096);
#pragma unroll
    for (int i = 0; i < 4; ++i)
      load_lds16(bG + (size_t)(i * 32 + brow) * I_DIM + ks + bcol, bDst + i * 4096);
    __syncthreads();

    short8 af[4];
    const int asl = (lane >> 4) ^ ((lane >> 1) & 3);
#pragma unroll
    for (int fm = 0; fm < 4; ++fm) {
      int m = wm * 64 + fm * 16 + (lane & 15);
      af[fm] = *(const short8*)((const char*)a_s + m * 64 + asl * 16);
    }
    const int k8 = (lane >> 4) * 8;
#pragma unroll
    for (int fn = 0; fn < 4; ++fn) {
      int n = wn * 64 + fn * 16 + (lane & 15);
      int s0 = (k8 >> 2) ^ (n & 7);
      int s1 = ((k8 >> 2) + 1) ^ (n & 7);
      f32x4 b0 = *(const f32x4*)(b_s + n * 32 + s0 * 4);
      f32x4 b1 = *(const f32x4*)(b_s + n * 32 + s1 * 4);
      short8 bb;
#pragma unroll
      for (int j = 0; j < 4; ++j) { bb[j] = f2bf(b0[j]); bb[j + 4] = f2bf(b1[j]); }
#pragma unroll
      for (int fm = 0; fm < 4; ++fm)
        acc[fm][fn] = __builtin_amdgcn_mfma_f32_16x16x32_bf16(af[fm], bb, acc[fm][fn], 0, 0, 0);
    }
    __syncthreads();
  }

#pragma unroll
  for (int fm = 0; fm < 4; ++fm) {
#pragma unroll
    for (int r = 0; r < 4; ++r) {
      int m = wm * 64 + fm * 16 + (lane >> 4) * 4 + r;
      if (mt * 128 + m < cnt) {
        int grow = off + mt * 128 + m;
        int tok = pos_token[grow];
        float wt = pos_w[grow];
#pragma unroll
        for (int fn = 0; fn < 4; ++fn) {
          int col = nt * 128 + wn * 64 + fn * 16 + (lane & 15);
          atomicAdd(out + (size_t)tok * H_DIM + col, wt * acc[fm][fn][r]);
        }
      }
    }
  }
}

// ---------------------------------------------------------------------------
extern "C" void kernel_launch(void* const* d_in, const int* in_sizes, int n_in,
                              void* d_out, int out_size, void* d_ws, size_t ws_size,
                              hipStream_t stream) {
  const float* x      = (const float*)d_in[0];
  const float* logits = (const float*)d_in[1];
  const float* w13    = (const float*)d_in[2];
  const float* w2     = (const float*)d_in[3];
  (void)d_in; (void)in_sizes; (void)n_in; (void)out_size; (void)ws_size;
  float* out = (float*)d_out;
  char* ws = (char*)d_ws;

  // ws layout (256B aligned), ~29.3 MB total
  size_t o = 0;
  auto alloc = [&](size_t bytes) { size_t r = o; o += (bytes + 255) & ~(size_t)255; return r; };
  short* xg        = (short*)(ws + alloc((size_t)NPAD * H_DIM * 2));
  short* act       = (short*)(ws + alloc((size_t)NPAD * I_DIM * 2));
  int*   pos_token = (int*)  (ws + alloc((size_t)NPOS * 4));
  float* pos_w     = (float*)(ws + alloc((size_t)NPOS * 4));
  int*   eoff      = (int*)  (ws + alloc((NEXP + 1) * 4));

  hipMemsetAsync(out, 0, (size_t)T_TOK * H_DIM * sizeof(float), stream);

  k_routing<<<1, 256, 0, stream>>>(logits, pos_token, pos_w, eoff);
  k_gather<<<NPOS, 256, 0, stream>>>(x, pos_token, xg);
  k_gateup<<<dim3(I_DIM / 128, 16, NEXP), 256, 0, stream>>>(xg, w13, eoff, act);
  k_down<<<dim3(H_DIM / 128, 16, NEXP), 256, 0, stream>>>(act, w2, eoff, pos_token, pos_w, out);
}

// Round 2
// 301.709 us; speedup vs baseline: 1.2056x; 1.2056x over previous
//
#include <hip/hip_runtime.h>
#include <hip/hip_bf16.h>
#include <stdint.h>

#define T_TOK 2048
#define H_DIM 2048
#define I_DIM 1408
#define NEXP  8
#define NPOS  4096   // T_TOK * top_k
#define NPAD  4224   // NPOS + 128 pad rows (tile overrun safety)

typedef short short8 __attribute__((ext_vector_type(8)));
typedef float f32x4  __attribute__((ext_vector_type(4)));

// f32 -> bf16 RNE (finite inputs only)
__device__ __forceinline__ short f2bf(float f) {
  union { float f; uint32_t u; } v; v.f = f;
  uint32_t r = (v.u + 0x7FFFu + ((v.u >> 16) & 1u)) >> 16;
  return (short)r;
}

// async global->LDS, 16B per lane. LDS dest = wave-uniform base + lane*16.
__device__ __forceinline__ void load_lds16(const void* g, void* l) {
  __builtin_amdgcn_global_load_lds((const __attribute__((address_space(1))) uint32_t*)g,
                                   (__attribute__((address_space(3))) uint32_t*)l,
                                   16, 0, 0);
}

// ---------------------------------------------------------------------------
// Kernel 0: f32 -> bf16 streaming cast (8 elems/thread/iter)
// ---------------------------------------------------------------------------
__global__ void k_cast(const float* __restrict__ src, short* __restrict__ dst, long n8) {
  long i = (long)blockIdx.x * blockDim.x + threadIdx.x;
  long stride = (long)gridDim.x * blockDim.x;
  for (; i < n8; i += stride) {
    const float4* s = (const float4*)(src + i * 8);
    float4 a = s[0], b = s[1];
    short8 o;
    o[0] = f2bf(a.x); o[1] = f2bf(a.y); o[2] = f2bf(a.z); o[3] = f2bf(a.w);
    o[4] = f2bf(b.x); o[5] = f2bf(b.y); o[6] = f2bf(b.z); o[7] = f2bf(b.w);
    ((short8*)dst)[i] = o;
  }
}

// ---------------------------------------------------------------------------
// Kernel 1: routing. Single block. top-2 of 8 logits, grouped by expert.
// ---------------------------------------------------------------------------
__global__ void k_routing(const float* __restrict__ logits,
                          int* __restrict__ pos_token,
                          float* __restrict__ pos_w,
                          int* __restrict__ eoff) {
  __shared__ int   s_ids[T_TOK];
  __shared__ float s_w0[T_TOK];
  __shared__ float s_w1[T_TOK];
  __shared__ int s_cnt[NEXP], s_cur[NEXP], s_off[NEXP + 1];
  const int tid = threadIdx.x;
  if (tid < NEXP) { s_cnt[tid] = 0; s_cur[tid] = 0; }
  __syncthreads();

  for (int t = tid; t < T_TOK; t += blockDim.x) {
    float l[NEXP];
#pragma unroll
    for (int e = 0; e < NEXP; ++e) l[e] = logits[t * NEXP + e];
    int b0 = 0; float v0 = l[0];
#pragma unroll
    for (int e = 1; e < NEXP; ++e) if (l[e] > v0) { v0 = l[e]; b0 = e; }
    int b1 = -1; float v1 = -1e30f;
#pragma unroll
    for (int e = 0; e < NEXP; ++e) if (e != b0 && l[e] > v1) { v1 = l[e]; b1 = e; }
    float t1 = __expf(v1 - v0);
    float w0 = 1.f / (1.f + t1);
    float w1 = 1.f - w0;
    s_ids[t] = b0 | (b1 << 8);
    s_w0[t] = w0; s_w1[t] = w1;
    atomicAdd(&s_cnt[b0], 1);
    atomicAdd(&s_cnt[b1], 1);
  }
  __syncthreads();
  if (tid == 0) {
    int acc = 0;
    for (int e = 0; e < NEXP; ++e) { s_off[e] = acc; acc += s_cnt[e]; }
    s_off[NEXP] = acc;
    for (int e = 0; e <= NEXP; ++e) eoff[e] = s_off[e];
  }
  __syncthreads();
  for (int t = tid; t < T_TOK; t += blockDim.x) {
    int ids = s_ids[t];
    int e0 = ids & 255, e1 = ids >> 8;
    int p0 = s_off[e0] + atomicAdd(&s_cur[e0], 1);
    pos_token[p0] = t; pos_w[p0] = s_w0[t];
    int p1 = s_off[e1] + atomicAdd(&s_cur[e1], 1);
    pos_token[p1] = t; pos_w[p1] = s_w1[t];
  }
}

// ---------------------------------------------------------------------------
// Kernel 2: gather+cast x rows into grouped order, bf16.
// ---------------------------------------------------------------------------
__global__ void k_gather(const float* __restrict__ x,
                         const int* __restrict__ pos_token,
                         short* __restrict__ xg) {
  const int p = blockIdx.x;
  const int tid = threadIdx.x;
  const int tok = pos_token[p];
  const float4* src = (const float4*)(x + (size_t)tok * H_DIM);
  float4 a = src[tid * 2];
  float4 b = src[tid * 2 + 1];
  short8 s;
  s[0] = f2bf(a.x); s[1] = f2bf(a.y); s[2] = f2bf(a.z); s[3] = f2bf(a.w);
  s[4] = f2bf(b.x); s[5] = f2bf(b.y); s[6] = f2bf(b.z); s[7] = f2bf(b.w);
  ((short8*)(xg + (size_t)p * H_DIM))[tid] = s;
}

// ---------------------------------------------------------------------------
// Kernel 3: grouped GEMM1 (gate 64-wide + up 64-wide per block), silu fused.
// 2-phase double-buffered LDS; XCD-chunked work swizzle (1 expert per XCD).
// Waves 2x2; per-wave out = 64x32 (gate) + 64x32 (up).
// ---------------------------------------------------------------------------
template<bool B16>
__global__ __launch_bounds__(256, 2) void k_gateup(
    const short* __restrict__ xg, const void* __restrict__ w13v,
    const int* __restrict__ eoff, short* __restrict__ act) {
  constexpr int BB = B16 ? 4096 : 8192;
  __shared__ __align__(16) char a_s[2][8192];
  __shared__ __align__(16) char b_s[2][2][BB];

  // XCD-chunked swizzle: nwg = 2816 = 8 * 352 (352 = 22 nt * 16 mt = 1 expert)
  const int wraw = blockIdx.x;
  const int w = (wraw & 7) * 352 + (wraw >> 3);
  const int e = w / 352;
  const int r = w % 352;
  const int nt = r >> 4;   // 0..21  (64-wide i-tile)
  const int mt = r & 15;   // 0..15

  const int off = eoff[e];
  const int cnt = eoff[e + 1] - off;
  if (mt * 128 >= cnt) return;

  const int tid = threadIdx.x;
  const int wid = tid >> 6;
  const int lane = tid & 63;
  const int wm = wid >> 1, wn = wid & 1;

  f32x4 accg[4][2] = {};
  f32x4 accu[4][2] = {};

  const short* aG = xg + (size_t)(off + mt * 128) * H_DIM;
  const char* bgG;
  const char* buG;
  if constexpr (B16) {
    const short* wb = (const short*)w13v;
    bgG = (const char*)(wb + (size_t)e * (2 * I_DIM) * H_DIM + (size_t)(nt * 64) * H_DIM);
    buG = bgG + (size_t)I_DIM * H_DIM * 2;
  } else {
    const float* wf = (const float*)w13v;
    bgG = (const char*)(wf + (size_t)e * (2 * I_DIM) * H_DIM + (size_t)(nt * 64) * H_DIM);
    buG = bgG + (size_t)I_DIM * H_DIM * 4;
  }

  // staging source coords (inverse-swizzled; LDS dest is linear tid*16)
  const int arow = tid >> 2;
  const int acol = ((tid & 3) ^ ((tid >> 3) & 3)) * 8;   // bf16 elems
  const int bfrow = tid >> 3;                            // f32 tile
  const int bfcol = ((tid & 7) ^ ((tid >> 3) & 7)) * 4;  // f32 elems

  auto stage = [&](int t, int bi) {
    const int ks = t * 32;
    char* ad = a_s[bi] + wid * 1024;
#pragma unroll
    for (int i = 0; i < 2; ++i)
      load_lds16(aG + (size_t)(i * 64 + arow) * H_DIM + ks + acol, ad + i * 4096);
    if constexpr (B16) {
      load_lds16((const short*)bgG + (size_t)arow * H_DIM + ks + acol, b_s[bi][0] + wid * 1024);
      load_lds16((const short*)buG + (size_t)arow * H_DIM + ks + acol, b_s[bi][1] + wid * 1024);
    } else {
#pragma unroll
      for (int i = 0; i < 2; ++i) {
        load_lds16((const float*)bgG + (size_t)(i * 32 + bfrow) * H_DIM + ks + bfcol,
                   b_s[bi][0] + wid * 1024 + i * 4096);
        load_lds16((const float*)buG + (size_t)(i * 32 + bfrow) * H_DIM + ks + bfcol,
                   b_s[bi][1] + wid * 1024 + i * 4096);
      }
    }
  };

  auto compute = [&](int bi) {
    const int asl = ((lane >> 4) ^ ((lane >> 1) & 3)) * 16;
    short8 af[4];
#pragma unroll
    for (int fm = 0; fm < 4; ++fm) {
      int m = wm * 64 + fm * 16 + (lane & 15);
      af[fm] = *(const short8*)(a_s[bi] + m * 64 + asl);
    }
#pragma unroll
    for (int fn = 0; fn < 2; ++fn) {
      int n = wn * 32 + fn * 16 + (lane & 15);
      short8 bg, bu;
      if constexpr (B16) {
        bg = *(const short8*)(b_s[bi][0] + n * 64 + asl);
        bu = *(const short8*)(b_s[bi][1] + n * 64 + asl);
      } else {
        const float* bgp = (const float*)b_s[bi][0];
        const float* bup = (const float*)b_s[bi][1];
        int k8 = (lane >> 4) * 8;
        int s0 = (k8 >> 2) ^ (n & 7);
        int s1 = ((k8 >> 2) + 1) ^ (n & 7);
        f32x4 g0 = *(const f32x4*)(bgp + n * 32 + s0 * 4);
        f32x4 g1 = *(const f32x4*)(bgp + n * 32 + s1 * 4);
        f32x4 u0 = *(const f32x4*)(bup + n * 32 + s0 * 4);
        f32x4 u1 = *(const f32x4*)(bup + n * 32 + s1 * 4);
#pragma unroll
        for (int j = 0; j < 4; ++j) {
          bg[j] = f2bf(g0[j]); bg[j + 4] = f2bf(g1[j]);
          bu[j] = f2bf(u0[j]); bu[j + 4] = f2bf(u1[j]);
        }
      }
#pragma unroll
      for (int fm = 0; fm < 4; ++fm)
        accg[fm][fn] = __builtin_amdgcn_mfma_f32_16x16x32_bf16(af[fm], bg, accg[fm][fn], 0, 0, 0);
#pragma unroll
      for (int fm = 0; fm < 4; ++fm)
        accu[fm][fn] = __builtin_amdgcn_mfma_f32_16x16x32_bf16(af[fm], bu, accu[fm][fn], 0, 0, 0);
    }
  };

  const int NK = H_DIM / 32;  // 64
  stage(0, 0);
  __syncthreads();
  for (int t = 0; t < NK; ++t) {
    int bi = t & 1;
    if (t + 1 < NK) stage(t + 1, bi ^ 1);
    compute(bi);
    __syncthreads();  // drains vmcnt(0): next tile ready; this tile's reads done
  }

  // epilogue: silu(g)*u -> bf16 act
#pragma unroll
  for (int fm = 0; fm < 4; ++fm) {
#pragma unroll
    for (int rr = 0; rr < 4; ++rr) {
      int m = wm * 64 + fm * 16 + (lane >> 4) * 4 + rr;
      if (mt * 128 + m < cnt) {
        size_t grow = (size_t)(off + mt * 128 + m);
#pragma unroll
        for (int fn = 0; fn < 2; ++fn) {
          int col = nt * 64 + wn * 32 + fn * 16 + (lane & 15);
          float g = accg[fm][fn][rr];
          float u = accu[fm][fn][rr];
          float a = g / (1.f + __expf(-g)) * u;
          act[grow * I_DIM + col] = f2bf(a);
        }
      }
    }
  }
}

// ---------------------------------------------------------------------------
// Kernel 4: grouped GEMM2: out[tok] += w * (act @ w2[e]^T). N-tile 64.
// ---------------------------------------------------------------------------
template<bool B16>
__global__ __launch_bounds__(256, 2) void k_down(
    const short* __restrict__ act, const void* __restrict__ w2v,
    const int* __restrict__ eoff, const int* __restrict__ pos_token,
    const float* __restrict__ pos_w, float* __restrict__ out) {
  constexpr int BB = B16 ? 4096 : 8192;
  __shared__ __align__(16) char a_s[2][8192];
  __shared__ __align__(16) char b_s[2][BB];

  // nwg = 4096 = 8 * 512 (512 = 32 nt * 16 mt = 1 expert)
  const int wraw = blockIdx.x;
  const int w = (wraw & 7) * 512 + (wraw >> 3);
  const int e = w >> 9;
  const int r = w & 511;
  const int nt = r >> 4;   // 0..31
  const int mt = r & 15;

  const int off = eoff[e];
  const int cnt = eoff[e + 1] - off;
  if (mt * 128 >= cnt) return;

  const int tid = threadIdx.x;
  const int wid = tid >> 6;
  const int lane = tid & 63;
  const int wm = wid >> 1, wn = wid & 1;

  f32x4 acc[4][2] = {};

  const short* aG = act + (size_t)(off + mt * 128) * I_DIM;
  const char* bG;
  if constexpr (B16) {
    const short* wb = (const short*)w2v;
    bG = (const char*)(wb + (size_t)e * H_DIM * I_DIM + (size_t)(nt * 64) * I_DIM);
  } else {
    const float* wf = (const float*)w2v;
    bG = (const char*)(wf + (size_t)e * H_DIM * I_DIM + (size_t)(nt * 64) * I_DIM);
  }

  const int arow = tid >> 2;
  const int acol = ((tid & 3) ^ ((tid >> 3) & 3)) * 8;
  const int bfrow = tid >> 3;
  const int bfcol = ((tid & 7) ^ ((tid >> 3) & 7)) * 4;

  auto stage = [&](int t, int bi) {
    const int ks = t * 32;
    char* ad = a_s[bi] + wid * 1024;
#pragma unroll
    for (int i = 0; i < 2; ++i)
      load_lds16(aG + (size_t)(i * 64 + arow) * I_DIM + ks + acol, ad + i * 4096);
    if constexpr (B16) {
      load_lds16((const short*)bG + (size_t)arow * I_DIM + ks + acol, b_s[bi] + wid * 1024);
    } else {
#pragma unroll
      for (int i = 0; i < 2; ++i)
        load_lds16((const float*)bG + (size_t)(i * 32 + bfrow) * I_DIM + ks + bfcol,
                   b_s[bi] + wid * 1024 + i * 4096);
    }
  };

  auto compute = [&](int bi) {
    const int asl = ((lane >> 4) ^ ((lane >> 1) & 3)) * 16;
    short8 af[4];
#pragma unroll
    for (int fm = 0; fm < 4; ++fm) {
      int m = wm * 64 + fm * 16 + (lane & 15);
      af[fm] = *(const short8*)(a_s[bi] + m * 64 + asl);
    }
#pragma unroll
    for (int fn = 0; fn < 2; ++fn) {
      int n = wn * 32 + fn * 16 + (lane & 15);
      short8 bb;
      if constexpr (B16) {
        bb = *(const short8*)(b_s[bi] + n * 64 + asl);
      } else {
        const float* bp = (const float*)b_s[bi];
        int k8 = (lane >> 4) * 8;
        int s0 = (k8 >> 2) ^ (n & 7);
        int s1 = ((k8 >> 2) + 1) ^ (n & 7);
        f32x4 b0 = *(const f32x4*)(bp + n * 32 + s0 * 4);
        f32x4 b1 = *(const f32x4*)(bp + n * 32 + s1 * 4);
#pragma unroll
        for (int j = 0; j < 4; ++j) { bb[j] = f2bf(b0[j]); bb[j + 4] = f2bf(b1[j]); }
      }
#pragma unroll
      for (int fm = 0; fm < 4; ++fm)
        acc[fm][fn] = __builtin_amdgcn_mfma_f32_16x16x32_bf16(af[fm], bb, acc[fm][fn], 0, 0, 0);
    }
  };

  const int NK = I_DIM / 32;  // 44
  stage(0, 0);
  __syncthreads();
  for (int t = 0; t < NK; ++t) {
    int bi = t & 1;
    if (t + 1 < NK) stage(t + 1, bi ^ 1);
    compute(bi);
    __syncthreads();
  }

#pragma unroll
  for (int fm = 0; fm < 4; ++fm) {
#pragma unroll
    for (int rr = 0; rr < 4; ++rr) {
      int m = wm * 64 + fm * 16 + (lane >> 4) * 4 + rr;
      if (mt * 128 + m < cnt) {
        int grow = off + mt * 128 + m;
        int tok = pos_token[grow];
        float wt = pos_w[grow];
#pragma unroll
        for (int fn = 0; fn < 2; ++fn) {
          int col = nt * 64 + wn * 32 + fn * 16 + (lane & 15);
          atomicAdd(out + (size_t)tok * H_DIM + col, wt * acc[fm][fn][rr]);
        }
      }
    }
  }
}

// ---------------------------------------------------------------------------
extern "C" void kernel_launch(void* const* d_in, const int* in_sizes, int n_in,
                              void* d_out, int out_size, void* d_ws, size_t ws_size,
                              hipStream_t stream) {
  const float* x      = (const float*)d_in[0];
  const float* logits = (const float*)d_in[1];
  const float* w13    = (const float*)d_in[2];
  const float* w2     = (const float*)d_in[3];
  (void)in_sizes; (void)n_in; (void)out_size;
  float* out = (float*)d_out;
  char* ws = (char*)d_ws;

  const size_t n_w13 = (size_t)NEXP * 2 * I_DIM * H_DIM;  // 46,137,344
  const size_t n_w2  = (size_t)NEXP * H_DIM * I_DIM;      // 23,068,672

  size_t o = 0;
  auto alloc = [&](size_t bytes) { size_t r = o; o += (bytes + 255) & ~(size_t)255; return r; };

  // full (bf16-weight) layout
  size_t off_wb13 = alloc(n_w13 * 2);
  size_t off_wb2  = alloc(n_w2 * 2);
  size_t off_xg   = alloc((size_t)NPAD * H_DIM * 2);
  size_t off_act  = alloc((size_t)NPAD * I_DIM * 2);
  size_t off_pt   = alloc((size_t)NPOS * 4);
  size_t off_pw   = alloc((size_t)NPOS * 4);
  size_t off_eo   = alloc((NEXP + 1) * 4);
  const bool b16 = (ws_size >= o);

  if (!b16) {  // fallback: small layout, f32 weights loaded directly
    o = 0;
    off_xg  = alloc((size_t)NPAD * H_DIM * 2);
    off_act = alloc((size_t)NPAD * I_DIM * 2);
    off_pt  = alloc((size_t)NPOS * 4);
    off_pw  = alloc((size_t)NPOS * 4);
    off_eo  = alloc((NEXP + 1) * 4);
  }

  short* wb13      = (short*)(ws + off_wb13);
  short* wb2       = (short*)(ws + off_wb2);
  short* xg        = (short*)(ws + off_xg);
  short* act       = (short*)(ws + off_act);
  int*   pos_token = (int*)  (ws + off_pt);
  float* pos_w     = (float*)(ws + off_pw);
  int*   eoff      = (int*)  (ws + off_eo);

  hipMemsetAsync(out, 0, (size_t)T_TOK * H_DIM * sizeof(float), stream);

  k_routing<<<1, 256, 0, stream>>>(logits, pos_token, pos_w, eoff);
  if (b16) {
    k_cast<<<4096, 256, 0, stream>>>(w13, wb13, (long)(n_w13 / 8));
    k_cast<<<4096, 256, 0, stream>>>(w2,  wb2,  (long)(n_w2 / 8));
  }
  k_gather<<<NPOS, 256, 0, stream>>>(x, pos_token, xg);
  if (b16) {
    k_gateup<true><<<2816, 256, 0, stream>>>(xg, (const void*)wb13, eoff, act);
    k_down<true><<<4096, 256, 0, stream>>>(act, (const void*)wb2, eoff, pos_token, pos_w, out);
  } else {
    k_gateup<false><<<2816, 256, 0, stream>>>(xg, (const void*)w13, eoff, act);
    k_down<false><<<4096, 256, 0, stream>>>(act, (const void*)w2, eoff, pos_token, pos_w, out);
  }
}

// Round 3
// 290.832 us; speedup vs baseline: 1.2507x; 1.0374x over previous
//
#include <hip/hip_runtime.h>
#include <hip/hip_bf16.h>
#include <stdint.h>

#define T_TOK 2048
#define H_DIM 2048
#define I_DIM 1408
#define NEXP  8
#define NPOS  4096   // T_TOK * top_k
#define NPAD  4224   // NPOS + 128 pad rows (tile overrun safety)

typedef short short8 __attribute__((ext_vector_type(8)));
typedef float f32x4  __attribute__((ext_vector_type(4)));

// f32 -> bf16 RNE (finite inputs only)
__device__ __forceinline__ short f2bf(float f) {
  union { float f; uint32_t u; } v; v.f = f;
  uint32_t r = (v.u + 0x7FFFu + ((v.u >> 16) & 1u)) >> 16;
  return (short)r;
}

// async global->LDS, 16B per lane. LDS dest = wave-uniform base + lane*16.
__device__ __forceinline__ void load_lds16(const void* g, void* l) {
  __builtin_amdgcn_global_load_lds((const __attribute__((address_space(1))) uint32_t*)g,
                                   (__attribute__((address_space(3))) uint32_t*)l,
                                   16, 0, 0);
}

// ---------------------------------------------------------------------------
// Kernel 0: f32 -> bf16 streaming cast (8 elems/thread/iter)
// ---------------------------------------------------------------------------
__global__ void k_cast(const float* __restrict__ src, short* __restrict__ dst, long n8) {
  long i = (long)blockIdx.x * blockDim.x + threadIdx.x;
  long stride = (long)gridDim.x * blockDim.x;
  for (; i < n8; i += stride) {
    const float4* s = (const float4*)(src + i * 8);
    float4 a = s[0], b = s[1];
    short8 o;
    o[0] = f2bf(a.x); o[1] = f2bf(a.y); o[2] = f2bf(a.z); o[3] = f2bf(a.w);
    o[4] = f2bf(b.x); o[5] = f2bf(b.y); o[6] = f2bf(b.z); o[7] = f2bf(b.w);
    ((short8*)dst)[i] = o;
  }
}

// ---------------------------------------------------------------------------
// Kernel 1: routing. Single block. top-2 of 8 logits, grouped by expert.
// ---------------------------------------------------------------------------
__global__ void k_routing(const float* __restrict__ logits,
                          int* __restrict__ pos_token,
                          float* __restrict__ pos_w,
                          int* __restrict__ eoff) {
  __shared__ int   s_ids[T_TOK];
  __shared__ float s_w0[T_TOK];
  __shared__ float s_w1[T_TOK];
  __shared__ int s_cnt[NEXP], s_cur[NEXP], s_off[NEXP + 1];
  const int tid = threadIdx.x;
  if (tid < NEXP) { s_cnt[tid] = 0; s_cur[tid] = 0; }
  __syncthreads();

  for (int t = tid; t < T_TOK; t += blockDim.x) {
    float l[NEXP];
#pragma unroll
    for (int e = 0; e < NEXP; ++e) l[e] = logits[t * NEXP + e];
    int b0 = 0; float v0 = l[0];
#pragma unroll
    for (int e = 1; e < NEXP; ++e) if (l[e] > v0) { v0 = l[e]; b0 = e; }
    int b1 = -1; float v1 = -1e30f;
#pragma unroll
    for (int e = 0; e < NEXP; ++e) if (e != b0 && l[e] > v1) { v1 = l[e]; b1 = e; }
    float t1 = __expf(v1 - v0);
    float w0 = 1.f / (1.f + t1);
    float w1 = 1.f - w0;
    s_ids[t] = b0 | (b1 << 8);
    s_w0[t] = w0; s_w1[t] = w1;
    atomicAdd(&s_cnt[b0], 1);
    atomicAdd(&s_cnt[b1], 1);
  }
  __syncthreads();
  if (tid == 0) {
    int acc = 0;
    for (int e = 0; e < NEXP; ++e) { s_off[e] = acc; acc += s_cnt[e]; }
    s_off[NEXP] = acc;
    for (int e = 0; e <= NEXP; ++e) eoff[e] = s_off[e];
  }
  __syncthreads();
  for (int t = tid; t < T_TOK; t += blockDim.x) {
    int ids = s_ids[t];
    int e0 = ids & 255, e1 = ids >> 8;
    int p0 = s_off[e0] + atomicAdd(&s_cur[e0], 1);
    pos_token[p0] = t; pos_w[p0] = s_w0[t];
    int p1 = s_off[e1] + atomicAdd(&s_cur[e1], 1);
    pos_token[p1] = t; pos_w[p1] = s_w1[t];
  }
}

// ---------------------------------------------------------------------------
// Kernel 2: gather+cast x rows into grouped order, bf16.
// ---------------------------------------------------------------------------
__global__ void k_gather(const float* __restrict__ x,
                         const int* __restrict__ pos_token,
                         short* __restrict__ xg) {
  const int p = blockIdx.x;
  const int tid = threadIdx.x;
  const int tok = pos_token[p];
  const float4* src = (const float4*)(x + (size_t)tok * H_DIM);
  float4 a = src[tid * 2];
  float4 b = src[tid * 2 + 1];
  short8 s;
  s[0] = f2bf(a.x); s[1] = f2bf(a.y); s[2] = f2bf(a.z); s[3] = f2bf(a.w);
  s[4] = f2bf(b.x); s[5] = f2bf(b.y); s[6] = f2bf(b.z); s[7] = f2bf(b.w);
  ((short8*)(xg + (size_t)p * H_DIM))[tid] = s;
}

// ---------------------------------------------------------------------------
// Kernel 3: grouped GEMM1, M64 x N64(gate+up), silu fused.
// 2-phase double-buffered LDS; expert-per-XCD chunked swizzle.
// Waves 2x2: each wave 32m x 32n over both gate and up (16 MFMA/K-step).
// ---------------------------------------------------------------------------
template<bool B16>
__global__ __launch_bounds__(256, 4) void k_gateup(
    const short* __restrict__ xg, const void* __restrict__ w13v,
    const int* __restrict__ eoff, short* __restrict__ act) {
  constexpr int BB = B16 ? 4096 : 8192;
  __shared__ __align__(16) char a_s[2][4096];
  __shared__ __align__(16) char b_s[2][2][BB];

  // nwg = 5632 = 8 * 704; 704 = 22 nt * 32 mt = one expert
  const int wraw = blockIdx.x;
  const int w = (wraw & 7) * 704 + (wraw >> 3);
  const int e = w / 704;
  const int r = w % 704;
  const int nt = r >> 5;   // 0..21  (64-wide i-tile)
  const int mt = r & 31;   // 0..31  (64-row m-tile)

  const int off = eoff[e];
  const int cnt = eoff[e + 1] - off;
  if (mt * 64 >= cnt) return;

  const int tid = threadIdx.x;
  const int wid = tid >> 6;
  const int lane = tid & 63;
  const int wm = wid >> 1, wn = wid & 1;

  f32x4 accg[2][2] = {};
  f32x4 accu[2][2] = {};

  const short* aG = xg + (size_t)(off + mt * 64) * H_DIM;
  const char* bgG;
  const char* buG;
  if constexpr (B16) {
    const short* wb = (const short*)w13v;
    bgG = (const char*)(wb + (size_t)e * (2 * I_DIM) * H_DIM + (size_t)(nt * 64) * H_DIM);
    buG = bgG + (size_t)I_DIM * H_DIM * 2;
  } else {
    const float* wf = (const float*)w13v;
    bgG = (const char*)(wf + (size_t)e * (2 * I_DIM) * H_DIM + (size_t)(nt * 64) * H_DIM);
    buG = bgG + (size_t)I_DIM * H_DIM * 4;
  }

  // staging source coords (inverse-swizzled; LDS dest linear tid*16)
  const int row  = tid >> 2;
  const int scol = ((tid & 3) ^ ((tid >> 3) & 3)) * 8;   // bf16 elems
  const int bfrow = tid >> 3;                            // f32 tile
  const int bfcol = ((tid & 7) ^ ((tid >> 3) & 7)) * 4;  // f32 elems

  auto stage = [&](int t, int bi) {
    const int ks = t * 32;
    load_lds16(aG + (size_t)row * H_DIM + ks + scol, a_s[bi] + wid * 1024);
    if constexpr (B16) {
      load_lds16((const short*)bgG + (size_t)row * H_DIM + ks + scol, b_s[bi][0] + wid * 1024);
      load_lds16((const short*)buG + (size_t)row * H_DIM + ks + scol, b_s[bi][1] + wid * 1024);
    } else {
#pragma unroll
      for (int i = 0; i < 2; ++i) {
        load_lds16((const float*)bgG + (size_t)(i * 32 + bfrow) * H_DIM + ks + bfcol,
                   b_s[bi][0] + wid * 1024 + i * 4096);
        load_lds16((const float*)buG + (size_t)(i * 32 + bfrow) * H_DIM + ks + bfcol,
                   b_s[bi][1] + wid * 1024 + i * 4096);
      }
    }
  };

  auto compute = [&](int bi) {
    const int asl = ((lane >> 4) ^ ((lane >> 1) & 3)) * 16;
    short8 af[2];
#pragma unroll
    for (int fm = 0; fm < 2; ++fm) {
      int m = wm * 32 + fm * 16 + (lane & 15);
      af[fm] = *(const short8*)(a_s[bi] + m * 64 + asl);
    }
#pragma unroll
    for (int fn = 0; fn < 2; ++fn) {
      int n = wn * 32 + fn * 16 + (lane & 15);
      short8 bg, bu;
      if constexpr (B16) {
        bg = *(const short8*)(b_s[bi][0] + n * 64 + asl);
        bu = *(const short8*)(b_s[bi][1] + n * 64 + asl);
      } else {
        const float* bgp = (const float*)b_s[bi][0];
        const float* bup = (const float*)b_s[bi][1];
        int k8 = (lane >> 4) * 8;
        int s0 = (k8 >> 2) ^ (n & 7);
        int s1 = ((k8 >> 2) + 1) ^ (n & 7);
        f32x4 g0 = *(const f32x4*)(bgp + n * 32 + s0 * 4);
        f32x4 g1 = *(const f32x4*)(bgp + n * 32 + s1 * 4);
        f32x4 u0 = *(const f32x4*)(bup + n * 32 + s0 * 4);
        f32x4 u1 = *(const f32x4*)(bup + n * 32 + s1 * 4);
#pragma unroll
        for (int j = 0; j < 4; ++j) {
          bg[j] = f2bf(g0[j]); bg[j + 4] = f2bf(g1[j]);
          bu[j] = f2bf(u0[j]); bu[j + 4] = f2bf(u1[j]);
        }
      }
#pragma unroll
      for (int fm = 0; fm < 2; ++fm)
        accg[fm][fn] = __builtin_amdgcn_mfma_f32_16x16x32_bf16(af[fm], bg, accg[fm][fn], 0, 0, 0);
#pragma unroll
      for (int fm = 0; fm < 2; ++fm)
        accu[fm][fn] = __builtin_amdgcn_mfma_f32_16x16x32_bf16(af[fm], bu, accu[fm][fn], 0, 0, 0);
    }
  };

  const int NK = H_DIM / 32;  // 64
  stage(0, 0);
  __syncthreads();
  for (int t = 0; t < NK; ++t) {
    int bi = t & 1;
    if (t + 1 < NK) stage(t + 1, bi ^ 1);
    compute(bi);
    __syncthreads();  // drains vmcnt(0): next tile staged; this tile's reads done
  }

  // epilogue: silu(g)*u -> bf16 act
#pragma unroll
  for (int fm = 0; fm < 2; ++fm) {
#pragma unroll
    for (int rr = 0; rr < 4; ++rr) {
      int m = wm * 32 + fm * 16 + (lane >> 4) * 4 + rr;
      if (mt * 64 + m < cnt) {
        size_t grow = (size_t)(off + mt * 64 + m);
#pragma unroll
        for (int fn = 0; fn < 2; ++fn) {
          int col = nt * 64 + wn * 32 + fn * 16 + (lane & 15);
          float g = accg[fm][fn][rr];
          float u = accu[fm][fn][rr];
          float a = g / (1.f + __expf(-g)) * u;
          act[grow * I_DIM + col] = f2bf(a);
        }
      }
    }
  }
}

// ---------------------------------------------------------------------------
// Kernel 4: grouped GEMM2: out[tok] += w * (act @ w2[e]^T). M64 x N64.
// ---------------------------------------------------------------------------
template<bool B16>
__global__ __launch_bounds__(256, 4) void k_down(
    const short* __restrict__ act, const void* __restrict__ w2v,
    const int* __restrict__ eoff, const int* __restrict__ pos_token,
    const float* __restrict__ pos_w, float* __restrict__ out) {
  constexpr int BB = B16 ? 4096 : 8192;
  __shared__ __align__(16) char a_s[2][4096];
  __shared__ __align__(16) char b_s[2][BB];

  // nwg = 8192 = 8 * 1024; 1024 = 32 nt * 32 mt = one expert
  const int wraw = blockIdx.x;
  const int w = (wraw & 7) * 1024 + (wraw >> 3);
  const int e = w >> 10;
  const int r = w & 1023;
  const int nt = r >> 5;   // 0..31
  const int mt = r & 31;   // 0..31

  const int off = eoff[e];
  const int cnt = eoff[e + 1] - off;
  if (mt * 64 >= cnt) return;

  const int tid = threadIdx.x;
  const int wid = tid >> 6;
  const int lane = tid & 63;
  const int wm = wid >> 1, wn = wid & 1;

  f32x4 acc[2][2] = {};

  const short* aG = act + (size_t)(off + mt * 64) * I_DIM;
  const char* bG;
  if constexpr (B16) {
    const short* wb = (const short*)w2v;
    bG = (const char*)(wb + (size_t)e * H_DIM * I_DIM + (size_t)(nt * 64) * I_DIM);
  } else {
    const float* wf = (const float*)w2v;
    bG = (const char*)(wf + (size_t)e * H_DIM * I_DIM + (size_t)(nt * 64) * I_DIM);
  }

  const int row  = tid >> 2;
  const int scol = ((tid & 3) ^ ((tid >> 3) & 3)) * 8;
  const int bfrow = tid >> 3;
  const int bfcol = ((tid & 7) ^ ((tid >> 3) & 7)) * 4;

  auto stage = [&](int t, int bi) {
    const int ks = t * 32;
    load_lds16(aG + (size_t)row * I_DIM + ks + scol, a_s[bi] + wid * 1024);
    if constexpr (B16) {
      load_lds16((const short*)bG + (size_t)row * I_DIM + ks + scol, b_s[bi] + wid * 1024);
    } else {
#pragma unroll
      for (int i = 0; i < 2; ++i)
        load_lds16((const float*)bG + (size_t)(i * 32 + bfrow) * I_DIM + ks + bfcol,
                   b_s[bi] + wid * 1024 + i * 4096);
    }
  };

  auto compute = [&](int bi) {
    const int asl = ((lane >> 4) ^ ((lane >> 1) & 3)) * 16;
    short8 af[2];
#pragma unroll
    for (int fm = 0; fm < 2; ++fm) {
      int m = wm * 32 + fm * 16 + (lane & 15);
      af[fm] = *(const short8*)(a_s[bi] + m * 64 + asl);
    }
#pragma unroll
    for (int fn = 0; fn < 2; ++fn) {
      int n = wn * 32 + fn * 16 + (lane & 15);
      short8 bb;
      if constexpr (B16) {
        bb = *(const short8*)(b_s[bi] + n * 64 + asl);
      } else {
        const float* bp = (const float*)b_s[bi];
        int k8 = (lane >> 4) * 8;
        int s0 = (k8 >> 2) ^ (n & 7);
        int s1 = ((k8 >> 2) + 1) ^ (n & 7);
        f32x4 b0 = *(const f32x4*)(bp + n * 32 + s0 * 4);
        f32x4 b1 = *(const f32x4*)(bp + n * 32 + s1 * 4);
#pragma unroll
        for (int j = 0; j < 4; ++j) { bb[j] = f2bf(b0[j]); bb[j + 4] = f2bf(b1[j]); }
      }
#pragma unroll
      for (int fm = 0; fm < 2; ++fm)
        acc[fm][fn] = __builtin_amdgcn_mfma_f32_16x16x32_bf16(af[fm], bb, acc[fm][fn], 0, 0, 0);
    }
  };

  const int NK = I_DIM / 32;  // 44
  stage(0, 0);
  __syncthreads();
  for (int t = 0; t < NK; ++t) {
    int bi = t & 1;
    if (t + 1 < NK) stage(t + 1, bi ^ 1);
    compute(bi);
    __syncthreads();
  }

#pragma unroll
  for (int fm = 0; fm < 2; ++fm) {
#pragma unroll
    for (int rr = 0; rr < 4; ++rr) {
      int m = wm * 32 + fm * 16 + (lane >> 4) * 4 + rr;
      if (mt * 64 + m < cnt) {
        int grow = off + mt * 64 + m;
        int tok = pos_token[grow];
        float wt = pos_w[grow];
#pragma unroll
        for (int fn = 0; fn < 2; ++fn) {
          int col = nt * 64 + wn * 32 + fn * 16 + (lane & 15);
          atomicAdd(out + (size_t)tok * H_DIM + col, wt * acc[fm][fn][rr]);
        }
      }
    }
  }
}

// ---------------------------------------------------------------------------
extern "C" void kernel_launch(void* const* d_in, const int* in_sizes, int n_in,
                              void* d_out, int out_size, void* d_ws, size_t ws_size,
                              hipStream_t stream) {
  const float* x      = (const float*)d_in[0];
  const float* logits = (const float*)d_in[1];
  const float* w13    = (const float*)d_in[2];
  const float* w2     = (const float*)d_in[3];
  (void)in_sizes; (void)n_in; (void)out_size;
  float* out = (float*)d_out;
  char* ws = (char*)d_ws;

  const size_t n_w13 = (size_t)NEXP * 2 * I_DIM * H_DIM;  // 46,137,344
  const size_t n_w2  = (size_t)NEXP * H_DIM * I_DIM;      // 23,068,672

  size_t o = 0;
  auto alloc = [&](size_t bytes) { size_t r = o; o += (bytes + 255) & ~(size_t)255; return r; };

  // full (bf16-weight) layout
  size_t off_wb13 = alloc(n_w13 * 2);
  size_t off_wb2  = alloc(n_w2 * 2);
  size_t off_xg   = alloc((size_t)NPAD * H_DIM * 2);
  size_t off_act  = alloc((size_t)NPAD * I_DIM * 2);
  size_t off_pt   = alloc((size_t)NPOS * 4);
  size_t off_pw   = alloc((size_t)NPOS * 4);
  size_t off_eo   = alloc((NEXP + 1) * 4);
  const bool b16 = (ws_size >= o);

  if (!b16) {  // fallback: small layout, f32 weights loaded directly
    o = 0;
    off_xg  = alloc((size_t)NPAD * H_DIM * 2);
    off_act = alloc((size_t)NPAD * I_DIM * 2);
    off_pt  = alloc((size_t)NPOS * 4);
    off_pw  = alloc((size_t)NPOS * 4);
    off_eo  = alloc((NEXP + 1) * 4);
  }

  short* wb13      = (short*)(ws + off_wb13);
  short* wb2       = (short*)(ws + off_wb2);
  short* xg        = (short*)(ws + off_xg);
  short* act       = (short*)(ws + off_act);
  int*   pos_token = (int*)  (ws + off_pt);
  float* pos_w     = (float*)(ws + off_pw);
  int*   eoff      = (int*)  (ws + off_eo);

  hipMemsetAsync(out, 0, (size_t)T_TOK * H_DIM * sizeof(float), stream);

  k_routing<<<1, 256, 0, stream>>>(logits, pos_token, pos_w, eoff);
  if (b16) {
    k_cast<<<4096, 256, 0, stream>>>(w13, wb13, (long)(n_w13 / 8));
    k_cast<<<4096, 256, 0, stream>>>(w2,  wb2,  (long)(n_w2 / 8));
  }
  k_gather<<<NPOS, 256, 0, stream>>>(x, pos_token, xg);
  if (b16) {
    k_gateup<true><<<5632, 256, 0, stream>>>(xg, (const void*)wb13, eoff, act);
    k_down<true><<<8192, 256, 0, stream>>>(act, (const void*)wb2, eoff, pos_token, pos_w, out);
  } else {
    k_gateup<false><<<5632, 256, 0, stream>>>(xg, (const void*)w13, eoff, act);
    k_down<false><<<8192, 256, 0, stream>>>(act, (const void*)w2, eoff, pos_token, pos_w, out);
  }
}

// Round 4
// 285.133 us; speedup vs baseline: 1.2757x; 1.0200x over previous
//
#include <hip/hip_runtime.h>
#include <hip/hip_bf16.h>
#include <stdint.h>

#define T_TOK 2048
#define H_DIM 2048
#define I_DIM 1408
#define NEXP  8
#define NPOS  4096   // T_TOK * top_k
#define NPAD  4224   // NPOS + 128 pad rows (tile overrun safety)

typedef short short8 __attribute__((ext_vector_type(8)));
typedef float f32x4  __attribute__((ext_vector_type(4)));

// f32 -> bf16 RNE (finite inputs only)
__device__ __forceinline__ short f2bf(float f) {
  union { float f; uint32_t u; } v; v.f = f;
  uint32_t r = (v.u + 0x7FFFu + ((v.u >> 16) & 1u)) >> 16;
  return (short)r;
}

// async global->LDS, 16B per lane. LDS dest = wave-uniform base + lane*16.
__device__ __forceinline__ void load_lds16(const void* g, void* l) {
  __builtin_amdgcn_global_load_lds((const __attribute__((address_space(1))) uint32_t*)g,
                                   (__attribute__((address_space(3))) uint32_t*)l,
                                   16, 0, 0);
}

// ---------------------------------------------------------------------------
// Kernel 0: f32 -> bf16 streaming cast (8 elems/thread/iter)
// ---------------------------------------------------------------------------
__global__ void k_cast(const float* __restrict__ src, short* __restrict__ dst, long n8) {
  long i = (long)blockIdx.x * blockDim.x + threadIdx.x;
  long stride = (long)gridDim.x * blockDim.x;
  for (; i < n8; i += stride) {
    const float4* s = (const float4*)(src + i * 8);
    float4 a = s[0], b = s[1];
    short8 o;
    o[0] = f2bf(a.x); o[1] = f2bf(a.y); o[2] = f2bf(a.z); o[3] = f2bf(a.w);
    o[4] = f2bf(b.x); o[5] = f2bf(b.y); o[6] = f2bf(b.z); o[7] = f2bf(b.w);
    ((short8*)dst)[i] = o;
  }
}

// ---------------------------------------------------------------------------
// Kernel 1: routing. Single block. top-2 of 8 logits, grouped by expert.
// ---------------------------------------------------------------------------
__global__ void k_routing(const float* __restrict__ logits,
                          int* __restrict__ pos_token,
                          float* __restrict__ pos_w,
                          int* __restrict__ eoff) {
  __shared__ int   s_ids[T_TOK];
  __shared__ float s_w0[T_TOK];
  __shared__ float s_w1[T_TOK];
  __shared__ int s_cnt[NEXP], s_cur[NEXP], s_off[NEXP + 1];
  const int tid = threadIdx.x;
  if (tid < NEXP) { s_cnt[tid] = 0; s_cur[tid] = 0; }
  __syncthreads();

  for (int t = tid; t < T_TOK; t += blockDim.x) {
    float l[NEXP];
#pragma unroll
    for (int e = 0; e < NEXP; ++e) l[e] = logits[t * NEXP + e];
    int b0 = 0; float v0 = l[0];
#pragma unroll
    for (int e = 1; e < NEXP; ++e) if (l[e] > v0) { v0 = l[e]; b0 = e; }
    int b1 = -1; float v1 = -1e30f;
#pragma unroll
    for (int e = 0; e < NEXP; ++e) if (e != b0 && l[e] > v1) { v1 = l[e]; b1 = e; }
    float t1 = __expf(v1 - v0);
    float w0 = 1.f / (1.f + t1);
    float w1 = 1.f - w0;
    s_ids[t] = b0 | (b1 << 8);
    s_w0[t] = w0; s_w1[t] = w1;
    atomicAdd(&s_cnt[b0], 1);
    atomicAdd(&s_cnt[b1], 1);
  }
  __syncthreads();
  if (tid == 0) {
    int acc = 0;
    for (int e = 0; e < NEXP; ++e) { s_off[e] = acc; acc += s_cnt[e]; }
    s_off[NEXP] = acc;
    for (int e = 0; e <= NEXP; ++e) eoff[e] = s_off[e];
  }
  __syncthreads();
  for (int t = tid; t < T_TOK; t += blockDim.x) {
    int ids = s_ids[t];
    int e0 = ids & 255, e1 = ids >> 8;
    int p0 = s_off[e0] + atomicAdd(&s_cur[e0], 1);
    pos_token[p0] = t; pos_w[p0] = s_w0[t];
    int p1 = s_off[e1] + atomicAdd(&s_cur[e1], 1);
    pos_token[p1] = t; pos_w[p1] = s_w1[t];
  }
}

// ---------------------------------------------------------------------------
// Kernel 2: gather+cast x rows into grouped order, bf16.
// ---------------------------------------------------------------------------
__global__ void k_gather(const float* __restrict__ x,
                         const int* __restrict__ pos_token,
                         short* __restrict__ xg) {
  const int p = blockIdx.x;
  const int tid = threadIdx.x;
  const int tok = pos_token[p];
  const float4* src = (const float4*)(x + (size_t)tok * H_DIM);
  float4 a = src[tid * 2];
  float4 b = src[tid * 2 + 1];
  short8 s;
  s[0] = f2bf(a.x); s[1] = f2bf(a.y); s[2] = f2bf(a.z); s[3] = f2bf(a.w);
  s[4] = f2bf(b.x); s[5] = f2bf(b.y); s[6] = f2bf(b.z); s[7] = f2bf(b.w);
  ((short8*)(xg + (size_t)p * H_DIM))[tid] = s;
}

// ---------------------------------------------------------------------------
// Kernel 3: grouped GEMM1, block = M128 x (64 gate + 64 up cols), silu fused.
// m97 wave economics: 4 waves 2x2, each wave 64m x (32g+32u):
//   per K32-step: 8 ds_read_b128 (4 A + 2 Bg + 2 Bu) feeding 16 MFMA.
// 2-phase double-buffered LDS (32 KB); expert-per-XCD block mapping.
// ---------------------------------------------------------------------------
__global__ __launch_bounds__(256, 2) void k_gateup(
    const short* __restrict__ xg, const short* __restrict__ wb13,
    const int* __restrict__ eoff, short* __restrict__ act) {
  __shared__ __align__(16) short a_s[2][128 * 32];   // 8 KB per buf
  __shared__ __align__(16) short bg_s[2][64 * 32];   // 4 KB per buf
  __shared__ __align__(16) short bu_s[2][64 * 32];   // 4 KB per buf

  // grid 5632 = 8 experts x 704; expert = wraw&7 (one expert per XCD slot)
  const int wraw = blockIdx.x;
  const int e = wraw & 7;
  const int r = wraw >> 3;       // 0..703
  const int nt = r >> 5;         // 0..21  (64-wide gate/up col tile)
  const int mt = r & 31;         // 0..31  (128-row m tile)

  const int off = eoff[e];
  const int cnt = eoff[e + 1] - off;
  if (mt * 128 >= cnt) return;

  const int tid = threadIdx.x;
  const int wid = tid >> 6;
  const int lane = tid & 63;
  const int wm = wid >> 1, wn = wid & 1;

  f32x4 accg[4][2] = {};
  f32x4 accu[4][2] = {};

  const short* aG  = xg + (size_t)(off + mt * 128) * H_DIM;
  const short* bgG = wb13 + (size_t)e * (2 * I_DIM) * H_DIM + (size_t)(nt * 64) * H_DIM;
  const short* buG = bgG + (size_t)I_DIM * H_DIM;

  // staging source coords (inverse-swizzled; LDS dest linear tid*16)
  const int row  = tid >> 2;                             // 0..63
  const int scol = ((tid & 3) ^ ((tid >> 3) & 3)) * 8;   // bf16 elems

  auto stage = [&](int t, int bi) {
    const int ks = t * 32;
    load_lds16(aG + (size_t)row * H_DIM + ks + scol,        (char*)a_s[bi] + wid * 1024);
    load_lds16(aG + (size_t)(64 + row) * H_DIM + ks + scol, (char*)a_s[bi] + 4096 + wid * 1024);
    load_lds16(bgG + (size_t)row * H_DIM + ks + scol,       (char*)bg_s[bi] + wid * 1024);
    load_lds16(buG + (size_t)row * H_DIM + ks + scol,       (char*)bu_s[bi] + wid * 1024);
  };

  auto compute = [&](int bi) {
    const int asl = ((lane >> 4) ^ ((lane >> 1) & 3)) * 16;
    short8 af[4];
#pragma unroll
    for (int fm = 0; fm < 4; ++fm) {
      int m = wm * 64 + fm * 16 + (lane & 15);
      af[fm] = *(const short8*)((const char*)a_s[bi] + m * 64 + asl);
    }
#pragma unroll
    for (int fn = 0; fn < 2; ++fn) {
      int n = wn * 32 + fn * 16 + (lane & 15);
      short8 bg = *(const short8*)((const char*)bg_s[bi] + n * 64 + asl);
      short8 bu = *(const short8*)((const char*)bu_s[bi] + n * 64 + asl);
#pragma unroll
      for (int fm = 0; fm < 4; ++fm)
        accg[fm][fn] = __builtin_amdgcn_mfma_f32_16x16x32_bf16(af[fm], bg, accg[fm][fn], 0, 0, 0);
#pragma unroll
      for (int fm = 0; fm < 4; ++fm)
        accu[fm][fn] = __builtin_amdgcn_mfma_f32_16x16x32_bf16(af[fm], bu, accu[fm][fn], 0, 0, 0);
    }
  };

  const int NK = H_DIM / 32;  // 64
  stage(0, 0);
  __syncthreads();
  for (int t = 0; t < NK; ++t) {
    int bi = t & 1;
    if (t + 1 < NK) stage(t + 1, bi ^ 1);
    compute(bi);
    __syncthreads();  // drains vmcnt(0): next tile staged; this tile's reads done
  }

  // epilogue: silu(g)*u -> bf16 act
#pragma unroll
  for (int fm = 0; fm < 4; ++fm) {
#pragma unroll
    for (int rr = 0; rr < 4; ++rr) {
      int m = wm * 64 + fm * 16 + (lane >> 4) * 4 + rr;
      if (mt * 128 + m < cnt) {
        size_t grow = (size_t)(off + mt * 128 + m);
#pragma unroll
        for (int fn = 0; fn < 2; ++fn) {
          int col = nt * 64 + wn * 32 + fn * 16 + (lane & 15);
          float g = accg[fm][fn][rr];
          float u = accu[fm][fn][rr];
          float a = g / (1.f + __expf(-g)) * u;
          act[grow * I_DIM + col] = f2bf(a);
        }
      }
    }
  }
}

// ---------------------------------------------------------------------------
// Kernel 4: grouped GEMM2: out[tok] += w * (act @ w2[e]^T).
// Block 128x128, wave 64x64 (4x4 fragments) — exact m97 economics.
// ---------------------------------------------------------------------------
__global__ __launch_bounds__(256, 2) void k_down(
    const short* __restrict__ act, const short* __restrict__ wb2,
    const int* __restrict__ eoff, const int* __restrict__ pos_token,
    const float* __restrict__ pos_w, float* __restrict__ out) {
  __shared__ __align__(16) short a_s[2][128 * 32];  // 8 KB per buf
  __shared__ __align__(16) short b_s[2][128 * 32];  // 8 KB per buf

  // grid 4096 = 8 experts x 512
  const int wraw = blockIdx.x;
  const int e = wraw & 7;
  const int r = wraw >> 3;     // 0..511
  const int nt = r >> 5;       // 0..15 (128-wide h tile)
  const int mt = r & 31;       // 0..31

  const int off = eoff[e];
  const int cnt = eoff[e + 1] - off;
  if (mt * 128 >= cnt) return;

  const int tid = threadIdx.x;
  const int wid = tid >> 6;
  const int lane = tid & 63;
  const int wm = wid >> 1, wn = wid & 1;

  f32x4 acc[4][4] = {};

  const short* aG = act + (size_t)(off + mt * 128) * I_DIM;
  const short* bG = wb2 + (size_t)e * H_DIM * I_DIM + (size_t)(nt * 128) * I_DIM;

  const int row  = tid >> 2;
  const int scol = ((tid & 3) ^ ((tid >> 3) & 3)) * 8;

  auto stage = [&](int t, int bi) {
    const int ks = t * 32;
    load_lds16(aG + (size_t)row * I_DIM + ks + scol,        (char*)a_s[bi] + wid * 1024);
    load_lds16(aG + (size_t)(64 + row) * I_DIM + ks + scol, (char*)a_s[bi] + 4096 + wid * 1024);
    load_lds16(bG + (size_t)row * I_DIM + ks + scol,        (char*)b_s[bi] + wid * 1024);
    load_lds16(bG + (size_t)(64 + row) * I_DIM + ks + scol, (char*)b_s[bi] + 4096 + wid * 1024);
  };

  auto compute = [&](int bi) {
    const int asl = ((lane >> 4) ^ ((lane >> 1) & 3)) * 16;
    short8 af[4];
#pragma unroll
    for (int fm = 0; fm < 4; ++fm) {
      int m = wm * 64 + fm * 16 + (lane & 15);
      af[fm] = *(const short8*)((const char*)a_s[bi] + m * 64 + asl);
    }
#pragma unroll
    for (int fn = 0; fn < 4; ++fn) {
      int n = wn * 64 + fn * 16 + (lane & 15);
      short8 bb = *(const short8*)((const char*)b_s[bi] + n * 64 + asl);
#pragma unroll
      for (int fm = 0; fm < 4; ++fm)
        acc[fm][fn] = __builtin_amdgcn_mfma_f32_16x16x32_bf16(af[fm], bb, acc[fm][fn], 0, 0, 0);
    }
  };

  const int NK = I_DIM / 32;  // 44
  stage(0, 0);
  __syncthreads();
  for (int t = 0; t < NK; ++t) {
    int bi = t & 1;
    if (t + 1 < NK) stage(t + 1, bi ^ 1);
    compute(bi);
    __syncthreads();
  }

#pragma unroll
  for (int fm = 0; fm < 4; ++fm) {
#pragma unroll
    for (int rr = 0; rr < 4; ++rr) {
      int m = wm * 64 + fm * 16 + (lane >> 4) * 4 + rr;
      if (mt * 128 + m < cnt) {
        int grow = off + mt * 128 + m;
        int tok = pos_token[grow];
        float wt = pos_w[grow];
#pragma unroll
        for (int fn = 0; fn < 4; ++fn) {
          int col = nt * 128 + wn * 64 + fn * 16 + (lane & 15);
          atomicAdd(out + (size_t)tok * H_DIM + col, wt * acc[fm][fn][rr]);
        }
      }
    }
  }
}

// ---------------------------------------------------------------------------
extern "C" void kernel_launch(void* const* d_in, const int* in_sizes, int n_in,
                              void* d_out, int out_size, void* d_ws, size_t ws_size,
                              hipStream_t stream) {
  const float* x      = (const float*)d_in[0];
  const float* logits = (const float*)d_in[1];
  const float* w13    = (const float*)d_in[2];
  const float* w2     = (const float*)d_in[3];
  (void)in_sizes; (void)n_in; (void)out_size; (void)ws_size;
  float* out = (float*)d_out;
  char* ws = (char*)d_ws;

  const size_t n_w13 = (size_t)NEXP * 2 * I_DIM * H_DIM;  // 46,137,344
  const size_t n_w2  = (size_t)NEXP * H_DIM * I_DIM;      // 23,068,672

  size_t o = 0;
  auto alloc = [&](size_t bytes) { size_t r = o; o += (bytes + 255) & ~(size_t)255; return r; };
  short* wb13      = (short*)(ws + alloc(n_w13 * 2));
  short* wb2       = (short*)(ws + alloc(n_w2 * 2));
  short* xg        = (short*)(ws + alloc((size_t)NPAD * H_DIM * 2));
  short* act       = (short*)(ws + alloc((size_t)NPAD * I_DIM * 2));
  int*   pos_token = (int*)  (ws + alloc((size_t)NPOS * 4));
  float* pos_w     = (float*)(ws + alloc((size_t)NPOS * 4));
  int*   eoff      = (int*)  (ws + alloc((NEXP + 1) * 4));

  hipMemsetAsync(out, 0, (size_t)T_TOK * H_DIM * sizeof(float), stream);

  k_routing<<<1, 256, 0, stream>>>(logits, pos_token, pos_w, eoff);
  k_cast<<<4096, 256, 0, stream>>>(w13, wb13, (long)(n_w13 / 8));
  k_cast<<<4096, 256, 0, stream>>>(w2,  wb2,  (long)(n_w2 / 8));
  k_gather<<<NPOS, 256, 0, stream>>>(x, pos_token, xg);
  k_gateup<<<5632, 256, 0, stream>>>(xg, wb13, eoff, act);
  k_down<<<4096, 256, 0, stream>>>(act, wb2, eoff, pos_token, pos_w, out);
}